// Round 1
// 2920.108 us; speedup vs baseline: 1.3061x; 1.3061x over previous
//
#include <hip/hip_runtime.h>
#include <hip/hip_bf16.h>

// Problem constants: B=32, T=512, D=768, H=256, K=32
// Outputs: d_out[0] = loss (f32), d_out[1 + b*512 + t] = preds as float.

#define NB 32
#define NT 512
#define ND 768
#define NH 256
#define NK 32

// ---------------------------------------------------------------------------
// K1: SGEMM  C[16384][2048] = x[16384][768] @ [W_ih_f | W_ih_b]^T
// 128x128 tile, 8x8 per thread, BK=16, fp32.  (verified round 3)
// ---------------------------------------------------------------------------
__global__ __launch_bounds__(256) void k_sgemm(const float* __restrict__ A,
                                               const float* __restrict__ Wf,
                                               const float* __restrict__ Wb,
                                               float* __restrict__ C) {
    __shared__ float As[16][132];
    __shared__ float Bs[16][132];
    const int tid = threadIdx.x;
    const int bx = blockIdx.x;   // n tile: 0..15
    const int by = blockIdx.y;   // m tile: 0..127
    const int tx = tid & 15, ty = tid >> 4;
    const int sm = tid >> 2;           // 0..63
    const int sk = (tid & 3) * 4;      // 0,4,8,12
    float acc[8][8];
#pragma unroll
    for (int i = 0; i < 8; ++i)
#pragma unroll
        for (int j = 0; j < 8; ++j) acc[i][j] = 0.f;

    for (int k0 = 0; k0 < ND; k0 += 16) {
#pragma unroll
        for (int h = 0; h < 2; ++h) {
            int m = sm + h * 64;
            float4 v = *(const float4*)(A + (size_t)(by * 128 + m) * ND + k0 + sk);
            As[sk + 0][m] = v.x; As[sk + 1][m] = v.y; As[sk + 2][m] = v.z; As[sk + 3][m] = v.w;
            int n = sm + h * 64;
            int gn = bx * 128 + n;
            const float* Wrow = (gn < 1024) ? (Wf + (size_t)gn * ND) : (Wb + (size_t)(gn - 1024) * ND);
            float4 w = *(const float4*)(Wrow + k0 + sk);
            Bs[sk + 0][n] = w.x; Bs[sk + 1][n] = w.y; Bs[sk + 2][n] = w.z; Bs[sk + 3][n] = w.w;
        }
        __syncthreads();
#pragma unroll
        for (int kk = 0; kk < 16; ++kk) {
            float a[8], b[8];
            *(float4*)&a[0] = *(const float4*)&As[kk][ty * 4];
            *(float4*)&a[4] = *(const float4*)&As[kk][64 + ty * 4];
            *(float4*)&b[0] = *(const float4*)&Bs[kk][tx * 4];
            *(float4*)&b[4] = *(const float4*)&Bs[kk][64 + tx * 4];
#pragma unroll
            for (int i = 0; i < 8; ++i)
#pragma unroll
                for (int j = 0; j < 8; ++j)
                    acc[i][j] = fmaf(a[i], b[j], acc[i][j]);
        }
        __syncthreads();
    }
#pragma unroll
    for (int i = 0; i < 8; ++i) {
        int m = by * 128 + ((i < 4) ? (ty * 4 + i) : (64 + ty * 4 + (i - 4)));
        float* Crow = C + (size_t)m * 2048 + bx * 128;
        *(float4*)(Crow + tx * 4)      = make_float4(acc[i][0], acc[i][1], acc[i][2], acc[i][3]);
        *(float4*)(Crow + 64 + tx * 4) = make_float4(acc[i][4], acc[i][5], acc[i][6], acc[i][7]);
    }
}

// ---------------------------------------------------------------------------
// K1.5: transpose W_hh into Wt4[(dir*256 + k)*256 + j] =
//   {W[0*256+j][k], W[1*256+j][k], W[2*256+j][k], W[3*256+j][k]}
// (verified round 3)
// ---------------------------------------------------------------------------
__global__ __launch_bounds__(256) void k_wt4(const float* __restrict__ Whf,
                                             const float* __restrict__ Whb,
                                             float4* __restrict__ Wt4) {
    int gid = blockIdx.x * 256 + threadIdx.x;
    if (gid >= 131072) return;
    int dir = gid >> 16;
    int k   = (gid >> 8) & 255;
    int j   = gid & 255;
    const float* W = dir ? Whb : Whf;
    Wt4[gid] = make_float4(W[(size_t)(0 * 256 + j) * 256 + k],
                           W[(size_t)(1 * 256 + j) * 256 + k],
                           W[(size_t)(2 * 256 + j) * 256 + k],
                           W[(size_t)(3 * 256 + j) * 256 + k]);
}

// ---------------------------------------------------------------------------
// K2: LSTM recurrence — register-resident W, j-split across 8 blocks/group.
// 128 blocks x 256 threads. group g = blockIdx&15 (dir=g>>3, batch-quad=g&7);
// j-slice s = blockIdx>>4 (j0=s*32). Each thread holds a 32k x 4gate W slice
// in 32 float4 VGPRs (loaded from the VERIFIED Wt4 layout).
//
// Cross-block h exchange: DATA-IS-THE-FLAG. h_f/h_b are pre-poisoned with
// the bit pattern 0xFFFFFFFF (a NaN; real h = sigm*tanh in (-1,1) can never
// equal it). Producers publish h with agent-scope relaxed atomic stores;
// consumers poll their 4 h values directly with agent-scope relaxed atomic
// loads until all 4 are non-sentinel. This removes the per-step counter
// barrier (8-way serialized fetch_add + tid0-spin + broadcast syncthreads +
// store-drain syncthreads) — ONE L3 round-trip per step instead of two.
// h slots are write-once per t (no WAR hazard); bit-pattern compare is
// immune to -ffast-math NaN folding.
// Precise expf/tanhf (Viterbi preds are sensitive to h error).
// ---------------------------------------------------------------------------
__device__ __forceinline__ float sigm(float x) { return 1.f / (1.f + expf(-x)); }

__global__ __launch_bounds__(256, 1) void k_lstm3(const float* __restrict__ C,
                                                  const float4* __restrict__ Wt4,
                                                  const float* __restrict__ b_f,
                                                  const float* __restrict__ b_b,
                                                  const int* __restrict__ lengths,
                                                  float* __restrict__ h_f,
                                                  float* __restrict__ h_b) {
    __shared__ float hsh[4][256];      // h(t-1) for the 4 batches
    __shared__ float4 part[256][4];    // [tid][batch] partial gate sums
    __shared__ float4 bias4[32];
    const int tid = threadIdx.x;
    const int g = blockIdx.x & 15, s = blockIdx.x >> 4;
    const int dir = g >> 3, bq = g & 7;
    const int j0 = s * 32, bg0 = bq * 4;
    const float* bias = dir ? b_b : b_f;
    float* hdir = dir ? h_b : h_f;

    if (tid < 32)
        bias4[tid] = make_float4(bias[j0 + tid], bias[256 + j0 + tid],
                                 bias[512 + j0 + tid], bias[768 + j0 + tid]);

    const int jj = tid & 31, kq = tid >> 5, k0 = kq * 32;
    float4 wreg[32];
    {
        const float4* wb = Wt4 + ((size_t)dir * 256 + k0) * 256 + j0 + jj;
#pragma unroll
        for (int i = 0; i < 32; ++i) wreg[i] = wb[(size_t)i * 256];
    }
    // reduction-thread mapping (tid < 128): batch cb_b, h-dim j0+cb_jj
    const int cb_jj = tid & 31, cb_b = (tid >> 5) & 3;
    const int myb = bg0 + cb_b;
    const int mylen = lengths[myb];
    float creg = 0.f;
    // cooperative h-load mapping: batch lb, k-range [lk, lk+4)
    const int lb = tid >> 6;
    const int lk = (tid & 63) * 4;
    __syncthreads();

    for (int t = 0; t < NT; ++t) {
        // prefetch this step's C row (read-only, overlaps the poll)
        float4 pre = make_float4(0.f, 0.f, 0.f, 0.f);
        if (tid < 128) {
            int src_t = t;
            if (dir) src_t = (t < mylen) ? (mylen - 1 - t) : t;
            const float* Crow = C + (size_t)(myb * 512 + src_t) * 2048 + dir * 1024 + j0 + cb_jj;
            pre.x = Crow[0]; pre.y = Crow[256]; pre.z = Crow[512]; pre.w = Crow[768];
        }
        if (t > 0) {
            // poll h(t-1) directly: data is the flag (sentinel 0xFFFFFFFF)
            const float* hp = hdir + ((size_t)(bg0 + lb) * 512 + (t - 1)) * 256 + lk;
            float v0, v1, v2, v3;
            int guard = 0;
            for (;;) {
                v0 = __hip_atomic_load(hp + 0, __ATOMIC_RELAXED, __HIP_MEMORY_SCOPE_AGENT);
                v1 = __hip_atomic_load(hp + 1, __ATOMIC_RELAXED, __HIP_MEMORY_SCOPE_AGENT);
                v2 = __hip_atomic_load(hp + 2, __ATOMIC_RELAXED, __HIP_MEMORY_SCOPE_AGENT);
                v3 = __hip_atomic_load(hp + 3, __ATOMIC_RELAXED, __HIP_MEMORY_SCOPE_AGENT);
                unsigned bad = (unsigned)(__float_as_uint(v0) == 0xFFFFFFFFu) |
                               (unsigned)(__float_as_uint(v1) == 0xFFFFFFFFu) |
                               (unsigned)(__float_as_uint(v2) == 0xFFFFFFFFu) |
                               (unsigned)(__float_as_uint(v3) == 0xFFFFFFFFu);
                if (!bad) break;
                if (++guard > (1 << 20)) break;   // liveness valve
            }
            hsh[lb][lk + 0] = v0; hsh[lb][lk + 1] = v1;
            hsh[lb][lk + 2] = v2; hsh[lb][lk + 3] = v3;
            __syncthreads();      // SYNC_A: hsh ready for all readers
        }
        float4 a0 = make_float4(0.f, 0.f, 0.f, 0.f), a1 = a0, a2 = a0, a3 = a0;
        if (t > 0) {
#pragma unroll
            for (int c = 0; c < 8; ++c) {
                float h0a[4], h1a[4], h2a[4], h3a[4];
                *(float4*)h0a = *(const float4*)&hsh[0][k0 + 4 * c];
                *(float4*)h1a = *(const float4*)&hsh[1][k0 + 4 * c];
                *(float4*)h2a = *(const float4*)&hsh[2][k0 + 4 * c];
                *(float4*)h3a = *(const float4*)&hsh[3][k0 + 4 * c];
#pragma unroll
                for (int i = 0; i < 4; ++i) {
                    float4 wv = wreg[c * 4 + i];
                    a0.x = fmaf(wv.x, h0a[i], a0.x); a0.y = fmaf(wv.y, h0a[i], a0.y);
                    a0.z = fmaf(wv.z, h0a[i], a0.z); a0.w = fmaf(wv.w, h0a[i], a0.w);
                    a1.x = fmaf(wv.x, h1a[i], a1.x); a1.y = fmaf(wv.y, h1a[i], a1.y);
                    a1.z = fmaf(wv.z, h1a[i], a1.z); a1.w = fmaf(wv.w, h1a[i], a1.w);
                    a2.x = fmaf(wv.x, h2a[i], a2.x); a2.y = fmaf(wv.y, h2a[i], a2.y);
                    a2.z = fmaf(wv.z, h2a[i], a2.z); a2.w = fmaf(wv.w, h2a[i], a2.w);
                    a3.x = fmaf(wv.x, h3a[i], a3.x); a3.y = fmaf(wv.y, h3a[i], a3.y);
                    a3.z = fmaf(wv.z, h3a[i], a3.z); a3.w = fmaf(wv.w, h3a[i], a3.w);
                }
            }
        }
        part[tid][0] = a0; part[tid][1] = a1; part[tid][2] = a2; part[tid][3] = a3;
        __syncthreads();          // SYNC_B: part ready for reducers
        if (tid < 128) {
            float4 b4 = bias4[cb_jj];
            float sx = pre.x + b4.x, sy = pre.y + b4.y, sz = pre.z + b4.z, sw = pre.w + b4.w;
#pragma unroll
            for (int q = 0; q < 8; ++q) {
                float4 p = part[q * 32 + cb_jj][cb_b];
                sx += p.x; sy += p.y; sz += p.z; sw += p.w;
            }
            float ig = sigm(sx), fg = sigm(sy), gt = tanhf(sz), og = sigm(sw);
            creg = fg * creg + ig * gt;
            float hn = og * tanhf(creg);
            float* hpo = hdir + ((size_t)myb * 512 + t) * 256 + j0 + cb_jj;
            __hip_atomic_store(hpo, hn, __ATOMIC_RELAXED, __HIP_MEMORY_SCOPE_AGENT);
        }
        // no trailing barrier: the store IS the publication; WAR on part[]
        // is covered by next iteration's SYNC_A, WAR on hsh by SYNC_B above.
    }
}

// ---------------------------------------------------------------------------
// K3: emissions  em[b][t][k] = hcat . W_clf[k] + b_clf[k]   (verified round 3)
// ---------------------------------------------------------------------------
__global__ __launch_bounds__(256) void k_em(const float* __restrict__ hf,
                                            const float* __restrict__ hb,
                                            const float* __restrict__ Wclf,
                                            const float* __restrict__ bclf,
                                            const int* __restrict__ lengths,
                                            float* __restrict__ em) {
    extern __shared__ float4 wc4[];   // [128][32]: wc4[jq*32+ko] = Wclf[ko][4jq..+3]
    const int tid = threadIdx.x;
    for (int idx = tid; idx < 4096; idx += 256) {
        int jq = idx >> 5, ko = idx & 31;
        wc4[idx] = *(const float4*)(Wclf + (size_t)ko * 512 + jq * 4);
    }
    __syncthreads();
    const int r = tid >> 5, ko = tid & 31;
    const int m = blockIdx.x * 8 + r;
    const int b = m >> 9, t = m & 511;
    const int len = lengths[b];
    const int rev = (t < len) ? (len - 1 - t) : t;
    const float* hfr = hf + (size_t)m * 256;
    const float* hbr = hb + (size_t)(b * 512 + rev) * 256;
    float acc = bclf[ko];
#pragma unroll 4
    for (int jq = 0; jq < 64; ++jq) {
        float4 h4 = *(const float4*)(hfr + jq * 4);
        float4 ww = wc4[jq * 32 + ko];
        acc += h4.x * ww.x + h4.y * ww.y + h4.z * ww.z + h4.w * ww.w;
    }
#pragma unroll 4
    for (int jq = 0; jq < 64; ++jq) {
        float4 h4 = *(const float4*)(hbr + jq * 4);
        float4 ww = wc4[(64 + jq) * 32 + ko];
        acc += h4.x * ww.x + h4.y * ww.y + h4.z * ww.z + h4.w * ww.w;
    }
    em[(size_t)m * 32 + ko] = acc;
}

// ---------------------------------------------------------------------------
// K4: CRF forward (logZ, num) and Viterbi (+backtrace).   (verified round 3)
// ---------------------------------------------------------------------------
__global__ __launch_bounds__(64) void k_crfvit(const float* __restrict__ em,
                                               const int* __restrict__ targets,
                                               const int* __restrict__ lengths,
                                               const float* __restrict__ start_t,
                                               const float* __restrict__ end_t,
                                               const float* __restrict__ trans,
                                               float* __restrict__ numv,
                                               float* __restrict__ logZv,
                                               float* __restrict__ out) {
    __shared__ float trans_s[32][33];
    __shared__ float vec[32];
    __shared__ unsigned char hist[511 * 32];
    const int tid = threadIdx.x;
    const int b = blockIdx.x & 31;
    const int mode = blockIdx.x >> 5;
    for (int idx = tid; idx < 1024; idx += 64) trans_s[idx >> 5][idx & 31] = trans[idx];
    const int len = lengths[b];
    const float* emb = em + (size_t)b * 512 * 32;
    const int k = tid & 31, half = tid >> 5;
    if (tid < 32) vec[tid] = start_t[tid] + emb[tid];
    __syncthreads();

    if (mode == 0) {
        for (int t = 1; t < NT; ++t) {
            bool mv = t < len;
            int kp0 = half * 16;
            float m = -1e30f;
#pragma unroll 4
            for (int i = 0; i < 16; ++i)
                m = fmaxf(m, vec[kp0 + i] + trans_s[kp0 + i][k]);
            float m2 = fmaxf(m, __shfl_xor(m, 32));
            float ssum = 0.f;
#pragma unroll 4
            for (int i = 0; i < 16; ++i)
                ssum += __expf(vec[kp0 + i] + trans_s[kp0 + i][k] - m2);
            ssum += __shfl_xor(ssum, 32);
            float anew = m2 + __logf(ssum) + emb[t * 32 + k];
            __syncthreads();
            if (half == 0 && mv) vec[k] = anew;
            __syncthreads();
        }
        float val = (tid < 32) ? vec[tid] + end_t[tid] : -1e30f;
        float m = val;
#pragma unroll
        for (int off = 32; off >= 1; off >>= 1) m = fmaxf(m, __shfl_xor(m, off));
        float e = (tid < 32) ? __expf(val - m) : 0.f;
#pragma unroll
        for (int off = 32; off >= 1; off >>= 1) e += __shfl_xor(e, off);
        if (tid == 0) logZv[b] = m + __logf(e);
        // numerator
        const int* tg = targets + b * 512;
        float partial = 0.f;
        for (int t = 1 + tid; t < NT; t += 64) {
            if (t < len) {
                int y0 = tg[t - 1], y1 = tg[t];
                partial += trans_s[y0][y1] + emb[t * 32 + y1];
            }
        }
#pragma unroll
        for (int off = 32; off >= 1; off >>= 1) partial += __shfl_xor(partial, off);
        if (tid == 0) {
            int y00 = tg[0];
            int yl = tg[len - 1];
            numv[b] = partial + start_t[y00] + emb[y00] + end_t[yl];
        }
    } else {
        for (int t = 1; t < NT; ++t) {
            bool mv = t < len;
            int kp0 = half * 16;
            float e = emb[t * 32 + k];
            float m = -1e30f; int mi = kp0;
#pragma unroll 4
            for (int i = 0; i < 16; ++i) {
                float v = (vec[kp0 + i] + trans_s[kp0 + i][k]) + e;
                if (v > m) { m = v; mi = kp0 + i; }
            }
            float mo = __shfl_xor(m, 32);
            int io = __shfl_xor(mi, 32);
            float mlow = half ? mo : m;   int ilow = half ? io : mi;
            float mhigh = half ? m : mo;  int ihigh = half ? mi : io;
            float bm; int bi;
            if (mhigh > mlow) { bm = mhigh; bi = ihigh; } else { bm = mlow; bi = ilow; }
            __syncthreads();
            if (half == 0) {
                hist[(t - 1) * 32 + k] = (unsigned char)(mv ? bi : k);
                if (mv) vec[k] = bm;
            }
            __syncthreads();
        }
        float val = (tid < 32) ? vec[tid] + end_t[tid] : -1e30f;
        int idx = (tid < 32) ? tid : 63;
#pragma unroll
        for (int off = 32; off >= 1; off >>= 1) {
            float vo = __shfl_xor(val, off);
            int io = __shfl_xor(idx, off);
            if (vo > val || (vo == val && io < idx)) { val = vo; idx = io; }
        }
        int cur = idx;
        float* ob = out + 1 + (size_t)b * 512;
        if (tid == 0) ob[511] = (511 < len) ? (float)cur : 0.f;
        for (int t2 = 510; t2 >= 0; --t2) {
            cur = hist[t2 * 32 + cur];
            if (tid == 0) ob[t2] = (t2 < len) ? (float)cur : 0.f;
        }
    }
}

// ---------------------------------------------------------------------------
// K5: loss = -mean(num - logZ)
// ---------------------------------------------------------------------------
__global__ __launch_bounds__(64) void k_loss(const float* __restrict__ numv,
                                             const float* __restrict__ logZv,
                                             float* __restrict__ out) {
    int tid = threadIdx.x;
    float v = (tid < 32) ? (logZv[tid] - numv[tid]) : 0.f;
#pragma unroll
    for (int off = 32; off >= 1; off >>= 1) v += __shfl_xor(v, off);
    if (tid == 0) out[0] = v / 32.f;
}

// ---------------------------------------------------------------------------
extern "C" void kernel_launch(void* const* d_in, const int* in_sizes, int n_in,
                              void* d_out, int out_size, void* d_ws, size_t ws_size,
                              hipStream_t stream) {
    const float* x       = (const float*)d_in[0];
    const int*   lengths = (const int*)d_in[1];
    // d_in[2] = mask (recomputed from lengths)
    const int*   targets = (const int*)d_in[3];
    const float* W_ih_f  = (const float*)d_in[4];
    const float* W_hh_f  = (const float*)d_in[5];
    const float* b_f     = (const float*)d_in[6];
    const float* W_ih_b  = (const float*)d_in[7];
    const float* W_hh_b  = (const float*)d_in[8];
    const float* b_b     = (const float*)d_in[9];
    const float* W_clf   = (const float*)d_in[10];
    const float* b_clf   = (const float*)d_in[11];
    const float* start_t = (const float*)d_in[12];
    const float* end_t   = (const float*)d_in[13];
    const float* trans   = (const float*)d_in[14];
    float* out = (float*)d_out;
    float* ws = (float*)d_ws;

    float* C     = ws;                                   // 16384*2048
    float* h_f   = C + (size_t)16384 * 2048;             // 32*512*256
    float* h_b   = h_f + (size_t)32 * 512 * 256;         // 32*512*256
    float* em    = h_b + (size_t)32 * 512 * 256;         // 32*512*32
    float4* Wt4  = (float4*)(em + (size_t)32 * 512 * 32);// 131072 float4
    float* numv  = (float*)(Wt4 + 131072);               // 32
    float* logZv = numv + 32;                            // 32

    // Re-poison h buffers with the sentinel bit pattern every launch
    // (graph-replay safe: this is the per-iteration reset of the data-flags).
    hipMemsetAsync(h_f, 0xFF, (size_t)2 * 32 * 512 * 256 * sizeof(float), stream);
    k_wt4<<<512, 256, 0, stream>>>(W_hh_f, W_hh_b, Wt4);
    k_sgemm<<<dim3(16, 128), 256, 0, stream>>>(x, W_ih_f, W_ih_b, C);
    k_lstm3<<<128, 256, 0, stream>>>(C, Wt4, b_f, b_b, lengths, h_f, h_b);
    k_em<<<2048, 256, 65536, stream>>>(h_f, h_b, W_clf, b_clf, lengths, em);
    k_crfvit<<<64, 64, 0, stream>>>(em, targets, lengths, start_t, end_t, trans, numv, logZv, out);
    k_loss<<<1, 64, 0, stream>>>(numv, logZv, out);
}

// Round 2
// 2476.947 us; speedup vs baseline: 1.5398x; 1.1789x over previous
//
#include <hip/hip_runtime.h>
#include <hip/hip_bf16.h>

// Problem constants: B=32, T=512, D=768, H=256, K=32
// Outputs: d_out[0] = loss (f32), d_out[1 + b*512 + t] = preds as float.

#define NB 32
#define NT 512
#define ND 768
#define NH 256
#define NK 32

// ---------------------------------------------------------------------------
// K1: SGEMM  C[16384][2048] = x[16384][768] @ [W_ih_f | W_ih_b]^T
// 128x128 tile, 8x8 per thread, BK=16, fp32.  (verified round 3)
// ---------------------------------------------------------------------------
__global__ __launch_bounds__(256) void k_sgemm(const float* __restrict__ A,
                                               const float* __restrict__ Wf,
                                               const float* __restrict__ Wb,
                                               float* __restrict__ C) {
    __shared__ float As[16][132];
    __shared__ float Bs[16][132];
    const int tid = threadIdx.x;
    const int bx = blockIdx.x;   // n tile: 0..15
    const int by = blockIdx.y;   // m tile: 0..127
    const int tx = tid & 15, ty = tid >> 4;
    const int sm = tid >> 2;           // 0..63
    const int sk = (tid & 3) * 4;      // 0,4,8,12
    float acc[8][8];
#pragma unroll
    for (int i = 0; i < 8; ++i)
#pragma unroll
        for (int j = 0; j < 8; ++j) acc[i][j] = 0.f;

    for (int k0 = 0; k0 < ND; k0 += 16) {
#pragma unroll
        for (int h = 0; h < 2; ++h) {
            int m = sm + h * 64;
            float4 v = *(const float4*)(A + (size_t)(by * 128 + m) * ND + k0 + sk);
            As[sk + 0][m] = v.x; As[sk + 1][m] = v.y; As[sk + 2][m] = v.z; As[sk + 3][m] = v.w;
            int n = sm + h * 64;
            int gn = bx * 128 + n;
            const float* Wrow = (gn < 1024) ? (Wf + (size_t)gn * ND) : (Wb + (size_t)(gn - 1024) * ND);
            float4 w = *(const float4*)(Wrow + k0 + sk);
            Bs[sk + 0][n] = w.x; Bs[sk + 1][n] = w.y; Bs[sk + 2][n] = w.z; Bs[sk + 3][n] = w.w;
        }
        __syncthreads();
#pragma unroll
        for (int kk = 0; kk < 16; ++kk) {
            float a[8], b[8];
            *(float4*)&a[0] = *(const float4*)&As[kk][ty * 4];
            *(float4*)&a[4] = *(const float4*)&As[kk][64 + ty * 4];
            *(float4*)&b[0] = *(const float4*)&Bs[kk][tx * 4];
            *(float4*)&b[4] = *(const float4*)&Bs[kk][64 + tx * 4];
#pragma unroll
            for (int i = 0; i < 8; ++i)
#pragma unroll
                for (int j = 0; j < 8; ++j)
                    acc[i][j] = fmaf(a[i], b[j], acc[i][j]);
        }
        __syncthreads();
    }
#pragma unroll
    for (int i = 0; i < 8; ++i) {
        int m = by * 128 + ((i < 4) ? (ty * 4 + i) : (64 + ty * 4 + (i - 4)));
        float* Crow = C + (size_t)m * 2048 + bx * 128;
        *(float4*)(Crow + tx * 4)      = make_float4(acc[i][0], acc[i][1], acc[i][2], acc[i][3]);
        *(float4*)(Crow + 64 + tx * 4) = make_float4(acc[i][4], acc[i][5], acc[i][6], acc[i][7]);
    }
}

// ---------------------------------------------------------------------------
// K1.5: transpose W_hh into Wt4[(dir*256 + k)*256 + j] =
//   {W[0*256+j][k], W[1*256+j][k], W[2*256+j][k], W[3*256+j][k]}
// (verified round 3)
// ---------------------------------------------------------------------------
__global__ __launch_bounds__(256) void k_wt4(const float* __restrict__ Whf,
                                             const float* __restrict__ Whb,
                                             float4* __restrict__ Wt4) {
    int gid = blockIdx.x * 256 + threadIdx.x;
    if (gid >= 131072) return;
    int dir = gid >> 16;
    int k   = (gid >> 8) & 255;
    int j   = gid & 255;
    const float* W = dir ? Whb : Whf;
    Wt4[gid] = make_float4(W[(size_t)(0 * 256 + j) * 256 + k],
                           W[(size_t)(1 * 256 + j) * 256 + k],
                           W[(size_t)(2 * 256 + j) * 256 + k],
                           W[(size_t)(3 * 256 + j) * 256 + k]);
}

// ---------------------------------------------------------------------------
// K2: LSTM recurrence — ONE CHAIN PER GROUP.
// 64 groups = (dir, batch); 4 blocks/group (j-slice 64); 256 blocks total,
// exactly 1 block/CU. Each thread: W slice of 64 k x 1 j x 4 gates in 64
// float4 VGPRs (~280 VGPR, 1 wave/SIMD, no spill under launch_bounds(256,1)).
// Per step: 256 FMAs/thread (half of previous layout), poll is ONE value
// per thread (data-is-the-flag, sentinel 0xFFFFFFFF = NaN; h in (-1,1)).
// hsh reads are wave-broadcast (conflict-free). Blocks {g, g+64, g+128,
// g+192} round-robin to the SAME XCD -> exchange stays XCD-local.
// Race structure identical to verified R1 scheme:
//   poll+hsh-write(t) | SYNC_A | FMA reads hsh + part write | SYNC_B |
//   reduce+store(t).  hsh WAR covered by SYNC_B(t-1)..SYNC_A(t) ordering;
//   part WAR covered by SYNC_B(t-1) read-before-SYNC_A(t) write-after.
// Precise expf/tanhf (Viterbi preds are sensitive to h error).
// ---------------------------------------------------------------------------
__device__ __forceinline__ float sigm(float x) { return 1.f / (1.f + expf(-x)); }

__global__ __launch_bounds__(256, 1) void k_lstm3(const float* __restrict__ C,
                                                  const float4* __restrict__ Wt4,
                                                  const float* __restrict__ b_f,
                                                  const float* __restrict__ b_b,
                                                  const int* __restrict__ lengths,
                                                  float* __restrict__ h_f,
                                                  float* __restrict__ h_b) {
    __shared__ float4 hsh4[64];        // h(t-1): 256 floats, one batch
    __shared__ float4 part[4][64];     // [k-quad][jj] partial gate sums
    __shared__ float4 bias4[64];
    const int tid = threadIdx.x;
    const int g = blockIdx.x & 63, s = blockIdx.x >> 6;
    const int b = g & 31, dir = g >> 5;
    const int j0 = s * 64;
    const float* bias = dir ? b_b : b_f;
    float* hdir = dir ? h_b : h_f;

    if (tid < 64)
        bias4[tid] = make_float4(bias[j0 + tid], bias[256 + j0 + tid],
                                 bias[512 + j0 + tid], bias[768 + j0 + tid]);

    const int jj = tid & 63, kq = tid >> 6;   // j-column, k-quad (64 k each)
    float4 wreg[64];
    {
        const float4* wb = Wt4 + ((size_t)dir * 256 + kq * 64) * 256 + j0 + jj;
#pragma unroll
        for (int i = 0; i < 64; ++i) wreg[i] = wb[(size_t)i * 256];
    }
    const int mylen = lengths[b];
    float creg = 0.f;
    float* hshf = (float*)hsh4;
    __syncthreads();

    for (int t = 0; t < NT; ++t) {
        // prefetch this step's C row (issued before the poll; consumed after
        // SYNC_B, so its latency hides under poll + FMA)
        float4 pre = make_float4(0.f, 0.f, 0.f, 0.f);
        if (tid < 64) {
            int src_t = t;
            if (dir) src_t = (t < mylen) ? (mylen - 1 - t) : t;
            const float* Crow = C + (size_t)(b * 512 + src_t) * 2048 + dir * 1024 + j0 + tid;
            pre.x = Crow[0]; pre.y = Crow[256]; pre.z = Crow[512]; pre.w = Crow[768];
        }
        if (t > 0) {
            // poll h(t-1): one value per thread; data is the flag
            const float* hp = hdir + ((size_t)b * 512 + (t - 1)) * 256 + tid;
            float v;
            int guard = 0;
            for (;;) {
                v = __hip_atomic_load(hp, __ATOMIC_RELAXED, __HIP_MEMORY_SCOPE_AGENT);
                if (__float_as_uint(v) != 0xFFFFFFFFu) break;
                if (++guard > (1 << 22)) break;   // liveness valve
            }
            hshf[tid] = v;
            __syncthreads();      // SYNC_A: hsh ready for all readers
        }
        float4 acc = make_float4(0.f, 0.f, 0.f, 0.f);
        if (t > 0) {
#pragma unroll
            for (int c = 0; c < 16; ++c) {
                float ha[4];
                *(float4*)ha = hsh4[kq * 16 + c];   // wave-broadcast read
#pragma unroll
                for (int i = 0; i < 4; ++i) {
                    float4 wv = wreg[c * 4 + i];
                    acc.x = fmaf(wv.x, ha[i], acc.x);
                    acc.y = fmaf(wv.y, ha[i], acc.y);
                    acc.z = fmaf(wv.z, ha[i], acc.z);
                    acc.w = fmaf(wv.w, ha[i], acc.w);
                }
            }
        }
        part[kq][jj] = acc;
        __syncthreads();          // SYNC_B: part ready for reducers
        if (tid < 64) {
            float4 b4 = bias4[tid];
            float sx = pre.x + b4.x, sy = pre.y + b4.y, sz = pre.z + b4.z, sw = pre.w + b4.w;
#pragma unroll
            for (int q = 0; q < 4; ++q) {
                float4 p = part[q][tid];
                sx += p.x; sy += p.y; sz += p.z; sw += p.w;
            }
            float ig = sigm(sx), fg = sigm(sy), gt = tanhf(sz), og = sigm(sw);
            creg = fg * creg + ig * gt;
            float hn = og * tanhf(creg);
            __hip_atomic_store(hdir + ((size_t)b * 512 + t) * 256 + j0 + tid,
                               hn, __ATOMIC_RELAXED, __HIP_MEMORY_SCOPE_AGENT);
        }
        // no trailing barrier: the store IS the publication (write-once slots)
    }
}

// ---------------------------------------------------------------------------
// K3: emissions  em[b][t][k] = hcat . W_clf[k] + b_clf[k]   (verified round 3)
// ---------------------------------------------------------------------------
__global__ __launch_bounds__(256) void k_em(const float* __restrict__ hf,
                                            const float* __restrict__ hb,
                                            const float* __restrict__ Wclf,
                                            const float* __restrict__ bclf,
                                            const int* __restrict__ lengths,
                                            float* __restrict__ em) {
    extern __shared__ float4 wc4[];   // [128][32]: wc4[jq*32+ko] = Wclf[ko][4jq..+3]
    const int tid = threadIdx.x;
    for (int idx = tid; idx < 4096; idx += 256) {
        int jq = idx >> 5, ko = idx & 31;
        wc4[idx] = *(const float4*)(Wclf + (size_t)ko * 512 + jq * 4);
    }
    __syncthreads();
    const int r = tid >> 5, ko = tid & 31;
    const int m = blockIdx.x * 8 + r;
    const int b = m >> 9, t = m & 511;
    const int len = lengths[b];
    const int rev = (t < len) ? (len - 1 - t) : t;
    const float* hfr = hf + (size_t)m * 256;
    const float* hbr = hb + (size_t)(b * 512 + rev) * 256;
    float acc = bclf[ko];
#pragma unroll 4
    for (int jq = 0; jq < 64; ++jq) {
        float4 h4 = *(const float4*)(hfr + jq * 4);
        float4 ww = wc4[jq * 32 + ko];
        acc += h4.x * ww.x + h4.y * ww.y + h4.z * ww.z + h4.w * ww.w;
    }
#pragma unroll 4
    for (int jq = 0; jq < 64; ++jq) {
        float4 h4 = *(const float4*)(hbr + jq * 4);
        float4 ww = wc4[(64 + jq) * 32 + ko];
        acc += h4.x * ww.x + h4.y * ww.y + h4.z * ww.z + h4.w * ww.w;
    }
    em[(size_t)m * 32 + ko] = acc;
}

// ---------------------------------------------------------------------------
// K4: CRF forward (logZ, num) and Viterbi (+backtrace).   (verified round 3)
// ---------------------------------------------------------------------------
__global__ __launch_bounds__(64) void k_crfvit(const float* __restrict__ em,
                                               const int* __restrict__ targets,
                                               const int* __restrict__ lengths,
                                               const float* __restrict__ start_t,
                                               const float* __restrict__ end_t,
                                               const float* __restrict__ trans,
                                               float* __restrict__ numv,
                                               float* __restrict__ logZv,
                                               float* __restrict__ out) {
    __shared__ float trans_s[32][33];
    __shared__ float vec[32];
    __shared__ unsigned char hist[511 * 32];
    const int tid = threadIdx.x;
    const int b = blockIdx.x & 31;
    const int mode = blockIdx.x >> 5;
    for (int idx = tid; idx < 1024; idx += 64) trans_s[idx >> 5][idx & 31] = trans[idx];
    const int len = lengths[b];
    const float* emb = em + (size_t)b * 512 * 32;
    const int k = tid & 31, half = tid >> 5;
    if (tid < 32) vec[tid] = start_t[tid] + emb[tid];
    __syncthreads();

    if (mode == 0) {
        for (int t = 1; t < NT; ++t) {
            bool mv = t < len;
            int kp0 = half * 16;
            float m = -1e30f;
#pragma unroll 4
            for (int i = 0; i < 16; ++i)
                m = fmaxf(m, vec[kp0 + i] + trans_s[kp0 + i][k]);
            float m2 = fmaxf(m, __shfl_xor(m, 32));
            float ssum = 0.f;
#pragma unroll 4
            for (int i = 0; i < 16; ++i)
                ssum += __expf(vec[kp0 + i] + trans_s[kp0 + i][k] - m2);
            ssum += __shfl_xor(ssum, 32);
            float anew = m2 + __logf(ssum) + emb[t * 32 + k];
            __syncthreads();
            if (half == 0 && mv) vec[k] = anew;
            __syncthreads();
        }
        float val = (tid < 32) ? vec[tid] + end_t[tid] : -1e30f;
        float m = val;
#pragma unroll
        for (int off = 32; off >= 1; off >>= 1) m = fmaxf(m, __shfl_xor(m, off));
        float e = (tid < 32) ? __expf(val - m) : 0.f;
#pragma unroll
        for (int off = 32; off >= 1; off >>= 1) e += __shfl_xor(e, off);
        if (tid == 0) logZv[b] = m + __logf(e);
        // numerator
        const int* tg = targets + b * 512;
        float partial = 0.f;
        for (int t = 1 + tid; t < NT; t += 64) {
            if (t < len) {
                int y0 = tg[t - 1], y1 = tg[t];
                partial += trans_s[y0][y1] + emb[t * 32 + y1];
            }
        }
#pragma unroll
        for (int off = 32; off >= 1; off >>= 1) partial += __shfl_xor(partial, off);
        if (tid == 0) {
            int y00 = tg[0];
            int yl = tg[len - 1];
            numv[b] = partial + start_t[y00] + emb[y00] + end_t[yl];
        }
    } else {
        for (int t = 1; t < NT; ++t) {
            bool mv = t < len;
            int kp0 = half * 16;
            float e = emb[t * 32 + k];
            float m = -1e30f; int mi = kp0;
#pragma unroll 4
            for (int i = 0; i < 16; ++i) {
                float v = (vec[kp0 + i] + trans_s[kp0 + i][k]) + e;
                if (v > m) { m = v; mi = kp0 + i; }
            }
            float mo = __shfl_xor(m, 32);
            int io = __shfl_xor(mi, 32);
            float mlow = half ? mo : m;   int ilow = half ? io : mi;
            float mhigh = half ? m : mo;  int ihigh = half ? mi : io;
            float bm; int bi;
            if (mhigh > mlow) { bm = mhigh; bi = ihigh; } else { bm = mlow; bi = ilow; }
            __syncthreads();
            if (half == 0) {
                hist[(t - 1) * 32 + k] = (unsigned char)(mv ? bi : k);
                if (mv) vec[k] = bm;
            }
            __syncthreads();
        }
        float val = (tid < 32) ? vec[tid] + end_t[tid] : -1e30f;
        int idx = (tid < 32) ? tid : 63;
#pragma unroll
        for (int off = 32; off >= 1; off >>= 1) {
            float vo = __shfl_xor(val, off);
            int io = __shfl_xor(idx, off);
            if (vo > val || (vo == val && io < idx)) { val = vo; idx = io; }
        }
        int cur = idx;
        float* ob = out + 1 + (size_t)b * 512;
        if (tid == 0) ob[511] = (511 < len) ? (float)cur : 0.f;
        for (int t2 = 510; t2 >= 0; --t2) {
            cur = hist[t2 * 32 + cur];
            if (tid == 0) ob[t2] = (t2 < len) ? (float)cur : 0.f;
        }
    }
}

// ---------------------------------------------------------------------------
// K5: loss = -mean(num - logZ)
// ---------------------------------------------------------------------------
__global__ __launch_bounds__(64) void k_loss(const float* __restrict__ numv,
                                             const float* __restrict__ logZv,
                                             float* __restrict__ out) {
    int tid = threadIdx.x;
    float v = (tid < 32) ? (logZv[tid] - numv[tid]) : 0.f;
#pragma unroll
    for (int off = 32; off >= 1; off >>= 1) v += __shfl_xor(v, off);
    if (tid == 0) out[0] = v / 32.f;
}

// ---------------------------------------------------------------------------
extern "C" void kernel_launch(void* const* d_in, const int* in_sizes, int n_in,
                              void* d_out, int out_size, void* d_ws, size_t ws_size,
                              hipStream_t stream) {
    const float* x       = (const float*)d_in[0];
    const int*   lengths = (const int*)d_in[1];
    // d_in[2] = mask (recomputed from lengths)
    const int*   targets = (const int*)d_in[3];
    const float* W_ih_f  = (const float*)d_in[4];
    const float* W_hh_f  = (const float*)d_in[5];
    const float* b_f     = (const float*)d_in[6];
    const float* W_ih_b  = (const float*)d_in[7];
    const float* W_hh_b  = (const float*)d_in[8];
    const float* b_b     = (const float*)d_in[9];
    const float* W_clf   = (const float*)d_in[10];
    const float* b_clf   = (const float*)d_in[11];
    const float* start_t = (const float*)d_in[12];
    const float* end_t   = (const float*)d_in[13];
    const float* trans   = (const float*)d_in[14];
    float* out = (float*)d_out;
    float* ws = (float*)d_ws;

    float* C     = ws;                                   // 16384*2048
    float* h_f   = C + (size_t)16384 * 2048;             // 32*512*256
    float* h_b   = h_f + (size_t)32 * 512 * 256;         // 32*512*256
    float* em    = h_b + (size_t)32 * 512 * 256;         // 32*512*32
    float4* Wt4  = (float4*)(em + (size_t)32 * 512 * 32);// 131072 float4
    float* numv  = (float*)(Wt4 + 131072);               // 32
    float* logZv = numv + 32;                            // 32

    // Re-poison h buffers with the sentinel bit pattern every launch
    // (graph-replay safe: this is the per-iteration reset of the data-flags).
    hipMemsetAsync(h_f, 0xFF, (size_t)2 * 32 * 512 * 256 * sizeof(float), stream);
    k_wt4<<<512, 256, 0, stream>>>(W_hh_f, W_hh_b, Wt4);
    k_sgemm<<<dim3(16, 128), 256, 0, stream>>>(x, W_ih_f, W_ih_b, C);
    k_lstm3<<<256, 256, 0, stream>>>(C, Wt4, b_f, b_b, lengths, h_f, h_b);
    k_em<<<2048, 256, 65536, stream>>>(h_f, h_b, W_clf, b_clf, lengths, em);
    k_crfvit<<<64, 64, 0, stream>>>(em, targets, lengths, start_t, end_t, trans, numv, logZv, out);
    k_loss<<<1, 64, 0, stream>>>(numv, logZv, out);
}